// Round 3
// baseline (386.638 us; speedup 1.0000x reference)
//
#include <hip/hip_runtime.h>

// GCN 2-layer for MI355X (gfx950), fp32 compute, bf16 intermediates.
// out[v] = relu( dinv[v]*( g[v] + sum_{u->v} g[u] ) + b ),  g = dinv .* (x @ W)
//
// CSR build avoids scattered-4B write amplification (R2: 56MB writes for a
// 3.2MB array) via bucketed two-phase:
//   A) scatter (src,dst) into 64-node bucket regions of ebuf
//      (bucket region start == rowstart[b<<6], no extra scan needed)
//   B) block-per-bucket: resolve final slot, csr writes land in ~4KB window
//      -> each 64B line fully written by one block -> ~1 writeback/line.

#define K_DIM 128

typedef unsigned short ushort_t;
typedef unsigned int uint_t;

__device__ inline float bf2f(ushort_t u) {
    return __uint_as_float(((uint_t)u) << 16);
}
__device__ inline ushort_t f2bf(float f) {   // round-to-nearest-even
    uint_t x = __float_as_uint(f);
    uint_t r = x + 0x7fffu + ((x >> 16) & 1u);
    return (ushort_t)(r >> 16);
}

__global__ void count_edges_kernel(const int* __restrict__ dst, int e, int* __restrict__ cnt) {
    int i = blockIdx.x * blockDim.x + threadIdx.x;
    if (i < e) atomicAdd(&cnt[dst[i]], 1);
}

// S1: per-block (1024-elem) sums of cnt.
__global__ __launch_bounds__(256) void block_sum_kernel(const int* __restrict__ cnt, int n,
                                                        int* __restrict__ bsum) {
    __shared__ int red[256];
    int t = threadIdx.x;
    int base = blockIdx.x * 1024 + t * 4;
    int s = 0;
    if (base + 3 < n) {
        int4 v = *(const int4*)&cnt[base];
        s = v.x + v.y + v.z + v.w;
    } else {
        for (int i = 0; i < 4; ++i) if (base + i < n) s += cnt[base + i];
    }
    red[t] = s;
    __syncthreads();
    for (int off = 128; off > 0; off >>= 1) {
        if (t < off) red[t] += red[t + off];
        __syncthreads();
    }
    if (t == 0) bsum[blockIdx.x] = red[0];
}

// S2: single-block inclusive scan of nb (<=1024) block sums, in place; writes rowstart[n].
__global__ __launch_bounds__(1024) void scan_bsum_kernel(int* __restrict__ bsum, int nb,
                                                         int* __restrict__ rowstart, int n) {
    __shared__ int sh[1024];
    int t = threadIdx.x;
    int v = (t < nb) ? bsum[t] : 0;
    sh[t] = v;
    __syncthreads();
    for (int off = 1; off < 1024; off <<= 1) {
        int w = (t >= off) ? sh[t - off] : 0;
        __syncthreads();
        sh[t] += w;
        __syncthreads();
    }
    if (t < nb) bsum[t] = sh[t];
    if (t == nb - 1) rowstart[n] = sh[t];
}

// S3: local exclusive scan + block offset; emits rowstart + dinv.
__global__ __launch_bounds__(256) void local_scan_kernel(const int* __restrict__ cnt, int n,
                                                         const int* __restrict__ bsum_incl,
                                                         int* __restrict__ rowstart,
                                                         float* __restrict__ dinv) {
    __shared__ int tsum[256];
    int b = blockIdx.x, t = threadIdx.x;
    int base = b * 1024 + t * 4;
    int v[4];
    int s = 0;
    #pragma unroll
    for (int i = 0; i < 4; ++i) {
        int idx = base + i;
        v[i] = (idx < n) ? cnt[idx] : 0;
        s += v[i];
    }
    tsum[t] = s;
    __syncthreads();
    for (int off = 1; off < 256; off <<= 1) {
        int w = (t >= off) ? tsum[t - off] : 0;
        __syncthreads();
        tsum[t] += w;
        __syncthreads();
    }
    int excl = (t == 0 ? 0 : tsum[t - 1]) + (b == 0 ? 0 : bsum_incl[b - 1]);
    #pragma unroll
    for (int i = 0; i < 4; ++i) {
        int idx = base + i;
        if (idx < n) {
            rowstart[idx] = excl;
            excl += v[i];
            dinv[idx] = rsqrtf((float)(v[i] + 1));   // +1 self loop
        }
    }
}

// Phase A: scatter (src,dst) into bucket regions of ebuf. bucket = dst>>6,
// region start = rowstart[bucket<<6].
__global__ void scatter_bucket_kernel(const int* __restrict__ src, const int* __restrict__ dst,
                                      int e, const int* __restrict__ rowstart,
                                      int* __restrict__ bslot, int2* __restrict__ ebuf) {
    int i = blockIdx.x * blockDim.x + threadIdx.x;
    if (i < e) {
        int d = dst[i];
        int s = src[i];
        int b = d >> 6;
        int pos = rowstart[b << 6] + atomicAdd(&bslot[b], 1);
        ebuf[pos] = make_int2(s, d);
    }
}

// Phase B: one block per bucket; resolve final csr position within the bucket's window.
__global__ __launch_bounds__(256) void bucket_fill_kernel(const int2* __restrict__ ebuf,
                                                          const int* __restrict__ rowstart,
                                                          int n, int* __restrict__ slot,
                                                          int* __restrict__ csr_src) {
    int b = blockIdx.x;
    int lo = rowstart[b << 6];
    int hi_node = min((b + 1) << 6, n);
    int hi = rowstart[hi_node];
    for (int idx = lo + threadIdx.x; idx < hi; idx += 256) {
        int2 e2 = ebuf[idx];
        int j = rowstart[e2.y] + atomicAdd(&slot[e2.y], 1);
        csr_src[j] = e2.x;
    }
}

// C_bf16[n,COLS] = dinv[row] * (A[n,128] @ W[128,COLS]).  64-row tiles, A in LDS.
template <int COLS>
__global__ __launch_bounds__(256) void gemm_scale_kernel(const float* __restrict__ A,
                                                         const float* __restrict__ W,
                                                         const float* __restrict__ dinv,
                                                         ushort_t* __restrict__ out, int n) {
    constexpr int CG  = COLS / 4;
    constexpr int RG  = 256 / CG;
    constexpr int RPT = 64 / RG;
    __shared__ float Asl[64][132];
    int t    = threadIdx.x;
    int row0 = blockIdx.x * 64;

    #pragma unroll
    for (int it = 0; it < 8; ++it) {
        int idx = (it * 256 + t) * 4;
        int r = idx >> 7;
        int k = idx & 127;
        int gr = row0 + r;
        float4 v = {0.f, 0.f, 0.f, 0.f};
        if (gr < n) v = *(const float4*)&A[gr * K_DIM + k];
        *(float4*)&Asl[r][k] = v;
    }
    __syncthreads();

    int cg = t % CG, rg = t / CG;
    int c0 = cg * 4;
    float acc[RPT][4];
    #pragma unroll
    for (int i = 0; i < RPT; ++i)
        for (int j = 0; j < 4; ++j) acc[i][j] = 0.f;

    for (int k = 0; k < K_DIM; ++k) {
        float4 w = *(const float4*)&W[k * COLS + c0];
        #pragma unroll
        for (int i = 0; i < RPT; ++i) {
            float a = Asl[rg * RPT + i][k];
            acc[i][0] = fmaf(a, w.x, acc[i][0]);
            acc[i][1] = fmaf(a, w.y, acc[i][1]);
            acc[i][2] = fmaf(a, w.z, acc[i][2]);
            acc[i][3] = fmaf(a, w.w, acc[i][3]);
        }
    }

    #pragma unroll
    for (int i = 0; i < RPT; ++i) {
        int r = row0 + rg * RPT + i;
        if (r < n) {
            float s = dinv[r];
            ushort4 o;
            o.x = f2bf(acc[i][0] * s);
            o.y = f2bf(acc[i][1] * s);
            o.z = f2bf(acc[i][2] * s);
            o.w = f2bf(acc[i][3] * s);
            *(ushort4*)&out[r * COLS + c0] = o;
        }
    }
}

// One wave per node, lane covers 2 features (128 cols), bf16 gather, fp32 out.
__global__ __launch_bounds__(256) void aggregate128_kernel(const ushort_t* __restrict__ g,
                                                           const int* __restrict__ rowstart,
                                                           const int* __restrict__ csr_src,
                                                           const float* __restrict__ dinv,
                                                           const float* __restrict__ bias,
                                                           float* __restrict__ out, int n) {
    int wave = threadIdx.x >> 6;
    int lane = threadIdx.x & 63;
    int v = blockIdx.x * 4 + wave;
    if (v >= n) return;
    int s    = __builtin_amdgcn_readfirstlane(rowstart[v]);
    int epos = __builtin_amdgcn_readfirstlane(rowstart[v + 1]);
    int col = lane * 2;
    uint_t u = *(const uint_t*)&g[(size_t)v * 128 + col];   // self loop
    float accx = __uint_as_float(u << 16);
    float accy = __uint_as_float(u & 0xffff0000u);
    float acc2x = 0.f, acc2y = 0.f;
    int j = s;
    for (; j + 3 < epos; j += 4) {
        int u0 = csr_src[j], u1 = csr_src[j + 1], u2 = csr_src[j + 2], u3 = csr_src[j + 3];
        uint_t m0 = *(const uint_t*)&g[(size_t)u0 * 128 + col];
        uint_t m1 = *(const uint_t*)&g[(size_t)u1 * 128 + col];
        uint_t m2 = *(const uint_t*)&g[(size_t)u2 * 128 + col];
        uint_t m3 = *(const uint_t*)&g[(size_t)u3 * 128 + col];
        accx  += __uint_as_float(m0 << 16) + __uint_as_float(m1 << 16);
        accy  += __uint_as_float(m0 & 0xffff0000u) + __uint_as_float(m1 & 0xffff0000u);
        acc2x += __uint_as_float(m2 << 16) + __uint_as_float(m3 << 16);
        acc2y += __uint_as_float(m2 & 0xffff0000u) + __uint_as_float(m3 & 0xffff0000u);
    }
    for (; j < epos; ++j) {
        int uu = csr_src[j];
        uint_t m = *(const uint_t*)&g[(size_t)uu * 128 + col];
        accx += __uint_as_float(m << 16);
        accy += __uint_as_float(m & 0xffff0000u);
    }
    accx += acc2x; accy += acc2y;
    float dv = dinv[v];
    float2 b = *(const float2*)&bias[col];
    float2 o = {fmaxf(fmaf(accx, dv, b.x), 0.f), fmaxf(fmaf(accy, dv, b.y), 0.f)};
    *(float2*)&out[(size_t)v * 128 + col] = o;
}

// One wave per node, lane covers 1 feature (64 cols), bf16 gather, fp32 out.
__global__ __launch_bounds__(256) void aggregate64_kernel(const ushort_t* __restrict__ g,
                                                          const int* __restrict__ rowstart,
                                                          const int* __restrict__ csr_src,
                                                          const float* __restrict__ dinv,
                                                          const float* __restrict__ bias,
                                                          float* __restrict__ out, int n) {
    int wave = threadIdx.x >> 6;
    int lane = threadIdx.x & 63;
    int v = blockIdx.x * 4 + wave;
    if (v >= n) return;
    int s    = __builtin_amdgcn_readfirstlane(rowstart[v]);
    int epos = __builtin_amdgcn_readfirstlane(rowstart[v + 1]);
    float acc = bf2f(g[(size_t)v * 64 + lane]);
    float acc2 = 0.f;
    int j = s;
    for (; j + 3 < epos; j += 4) {
        int u0 = csr_src[j], u1 = csr_src[j + 1], u2 = csr_src[j + 2], u3 = csr_src[j + 3];
        float m0 = bf2f(g[(size_t)u0 * 64 + lane]);
        float m1 = bf2f(g[(size_t)u1 * 64 + lane]);
        float m2 = bf2f(g[(size_t)u2 * 64 + lane]);
        float m3 = bf2f(g[(size_t)u3 * 64 + lane]);
        acc += m0 + m1;
        acc2 += m2 + m3;
    }
    for (; j < epos; ++j) {
        int u = csr_src[j];
        acc += bf2f(g[(size_t)u * 64 + lane]);
    }
    acc += acc2;
    float o = fmaxf(fmaf(acc, dinv[v], bias[lane]), 0.f);
    out[(size_t)v * 64 + lane] = o;
}

extern "C" void kernel_launch(void* const* d_in, const int* in_sizes, int n_in,
                              void* d_out, int out_size, void* d_ws, size_t ws_size,
                              hipStream_t stream) {
    const float* x  = (const float*)d_in[0];
    const int*   ei = (const int*)d_in[1];   // [2, E] int32
    const float* W1 = (const float*)d_in[2];
    const float* b1 = (const float*)d_in[3];
    const float* W2 = (const float*)d_in[4];
    const float* b2 = (const float*)d_in[5];
    float* out = (float*)d_out;

    const int n = in_sizes[0] / 128;   // 50000
    const int e = in_sizes[1] / 2;     // 800000
    const int* src = ei;
    const int* dst = ei + e;
    const int nbuck = (n + 63) >> 6;   // 782 buckets of 64 dst nodes

    char* ws = (char*)d_ws;
    size_t off = 0;
    auto carve = [&](size_t bytes) -> void* {
        void* p = ws + off;
        off = (off + bytes + 255) & ~(size_t)255;
        return p;
    };
    int*      cnt      = (int*)     carve((size_t)n * 4);
    int*      bslot    = (int*)     carve((size_t)nbuck * 4);   // adjacent to cnt: one memset
    int*      rowstart = (int*)     carve((size_t)(n + 1) * 4);
    float*    dinv     = (float*)   carve((size_t)n * 4);
    int*      bsum     = (int*)     carve((size_t)1024 * 4);
    int2*     ebuf     = (int2*)    carve((size_t)e * 8);
    int*      csr_src  = (int*)     carve((size_t)e * 4);
    ushort_t* g1       = (ushort_t*)carve((size_t)n * 128 * 2);
    float*    h2       = (float*)   carve((size_t)n * 128 * 4);
    ushort_t* g2       = (ushort_t*)carve((size_t)n * 64 * 2);
    (void)ws_size;

    const int eblocks = (e + 255) / 256;
    const int nb      = (n + 1023) / 1024;

    // zero cnt + bslot in one shot (contiguous carve region)
    hipMemsetAsync(cnt, 0, (size_t)((char*)(bslot + nbuck) - (char*)cnt), stream);
    count_edges_kernel<<<eblocks, 256, 0, stream>>>(dst, e, cnt);
    block_sum_kernel<<<nb, 256, 0, stream>>>(cnt, n, bsum);
    scan_bsum_kernel<<<1, 1024, 0, stream>>>(bsum, nb, rowstart, n);
    local_scan_kernel<<<nb, 256, 0, stream>>>(cnt, n, bsum, rowstart, dinv);
    scatter_bucket_kernel<<<eblocks, 256, 0, stream>>>(src, dst, e, rowstart, bslot, ebuf);
    hipMemsetAsync(cnt, 0, (size_t)n * 4, stream);   // reuse as per-dst fill slots
    bucket_fill_kernel<<<nbuck, 256, 0, stream>>>(ebuf, rowstart, n, cnt, csr_src);

    const int gblocks = (n + 63) / 64;
    const int ablocks = (n + 3) / 4;

    gemm_scale_kernel<128><<<gblocks, 256, 0, stream>>>(x, W1, dinv, g1, n);
    aggregate128_kernel<<<ablocks, 256, 0, stream>>>(g1, rowstart, csr_src, dinv, b1, h2, n);
    gemm_scale_kernel<64><<<gblocks, 256, 0, stream>>>(h2, W2, dinv, g2, n);
    aggregate64_kernel<<<ablocks, 256, 0, stream>>>(g2, rowstart, csr_src, dinv, b2, out, n);
}

// Round 4
// 163.603 us; speedup vs baseline: 2.3633x; 2.3633x over previous
//
#include <hip/hip_runtime.h>

// GCN 2-layer for MI355X (gfx950). fp32 GEMM, bf16 intermediates, fp32 out.
// out[v] = relu( dinv[v]*( g[v] + sum_{u->v} g[u] ) + b ),  g = dinv .* (x @ W)
//
// R3 lesson: global atomics are the enemy (191us for 800k adds on 782 counters;
// ~50us for 800k adds on 50k counters). This version builds CSR with ZERO
// global atomics: LDS histograms + flat exclusive scan (radix partition),
// then per-bucket kernels whose writes land in small windows.
// R3 lesson 2: aggregation is latency-bound, not BW-bound (fp32->bf16 changed
// nothing). Gather now uses 4 edges/wave x 16B/lane => 4-8 rows in flight.

#define NPB 64    // nodes per bucket (power of 2)
#define PB  128   // partition chunk-blocks

typedef unsigned short ushort_t;
typedef unsigned int uint_t;

__device__ inline float bf2f_lo(uint_t u) { return __uint_as_float(u << 16); }
__device__ inline float bf2f_hi(uint_t u) { return __uint_as_float(u & 0xffff0000u); }
__device__ inline ushort_t f2bf(float f) {   // round-to-nearest-even
    uint_t x = __float_as_uint(f);
    uint_t r = x + 0x7fffu + ((x >> 16) & 1u);
    return (ushort_t)(r >> 16);
}

// ---------- generic 3-stage exclusive scan machinery ----------

__global__ __launch_bounds__(256) void block_sum_kernel(const int* __restrict__ a, int L,
                                                        int* __restrict__ bsum) {
    __shared__ int red[256];
    int t = threadIdx.x;
    int base = blockIdx.x * 1024 + t * 4;
    int s = 0;
    if (base + 3 < L) {
        int4 v = *(const int4*)&a[base];
        s = v.x + v.y + v.z + v.w;
    } else {
        for (int i = 0; i < 4; ++i) if (base + i < L) s += a[base + i];
    }
    red[t] = s;
    __syncthreads();
    for (int off = 128; off > 0; off >>= 1) {
        if (t < off) red[t] += red[t + off];
        __syncthreads();
    }
    if (t == 0) bsum[blockIdx.x] = red[0];
}

// single-block inclusive scan of nb (<=1024) block sums in place; *total_slot = grand total
__global__ __launch_bounds__(1024) void scan_bsum_kernel(int* __restrict__ bsum, int nb,
                                                         int* __restrict__ total_slot) {
    __shared__ int sh[1024];
    int t = threadIdx.x;
    int v = (t < nb) ? bsum[t] : 0;
    sh[t] = v;
    __syncthreads();
    for (int off = 1; off < 1024; off <<= 1) {
        int w = (t >= off) ? sh[t - off] : 0;
        __syncthreads();
        sh[t] += w;
        __syncthreads();
    }
    if (t < nb) bsum[t] = sh[t];
    if (t == nb - 1) *total_slot = sh[t];
}

// node variant: reads cnt, writes exclusive rowstart + dinv
__global__ __launch_bounds__(256) void local_scan_kernel(const int* __restrict__ cnt, int n,
                                                         const int* __restrict__ bsum_incl,
                                                         int* __restrict__ rowstart,
                                                         float* __restrict__ dinv) {
    __shared__ int tsum[256];
    int b = blockIdx.x, t = threadIdx.x;
    int base = b * 1024 + t * 4;
    int v[4];
    int s = 0;
    #pragma unroll
    for (int i = 0; i < 4; ++i) {
        int idx = base + i;
        v[i] = (idx < n) ? cnt[idx] : 0;
        s += v[i];
    }
    tsum[t] = s;
    __syncthreads();
    for (int off = 1; off < 256; off <<= 1) {
        int w = (t >= off) ? tsum[t - off] : 0;
        __syncthreads();
        tsum[t] += w;
        __syncthreads();
    }
    int excl = (t == 0 ? 0 : tsum[t - 1]) + (b == 0 ? 0 : bsum_incl[b - 1]);
    #pragma unroll
    for (int i = 0; i < 4; ++i) {
        int idx = base + i;
        if (idx < n) {
            rowstart[idx] = excl;
            excl += v[i];
            dinv[idx] = rsqrtf((float)(v[i] + 1));   // +1 self loop
        }
    }
}

// in-place variant for the flat histogram (no dinv)
__global__ __launch_bounds__(256) void local_scan_apply_kernel(int* __restrict__ arr, int L,
                                                               const int* __restrict__ bsum_incl) {
    __shared__ int tsum[256];
    int b = blockIdx.x, t = threadIdx.x;
    int base = b * 1024 + t * 4;
    int v[4];
    int s = 0;
    #pragma unroll
    for (int i = 0; i < 4; ++i) {
        int idx = base + i;
        v[i] = (idx < L) ? arr[idx] : 0;
        s += v[i];
    }
    tsum[t] = s;
    __syncthreads();
    for (int off = 1; off < 256; off <<= 1) {
        int w = (t >= off) ? tsum[t - off] : 0;
        __syncthreads();
        tsum[t] += w;
        __syncthreads();
    }
    int excl = (t == 0 ? 0 : tsum[t - 1]) + (b == 0 ? 0 : bsum_incl[b - 1]);
    #pragma unroll
    for (int i = 0; i < 4; ++i) {
        int idx = base + i;
        if (idx < L) {
            arr[idx] = excl;
            excl += v[i];
        }
    }
}

// ---------- radix partition (no global atomics) ----------

// P1: per chunk-block LDS histogram over buckets -> hist[k*PB + b]
__global__ __launch_bounds__(256) void bucket_hist_kernel(const int* __restrict__ dst, int e,
                                                          int epb, int K,
                                                          int* __restrict__ hist) {
    __shared__ int lh[1024];
    int t = threadIdx.x, b = blockIdx.x;
    for (int k = t; k < K; k += 256) lh[k] = 0;
    __syncthreads();
    int lo = b * epb, hi = min(lo + epb, e);
    for (int i = lo + t; i < hi; i += 256) atomicAdd(&lh[dst[i] >> 6], 1);
    __syncthreads();
    for (int k = t; k < K; k += 256) hist[k * PB + b] = lh[k];
}

// P3: scatter packed (src | dlocal<<16) into bucket regions (requires n <= 65536)
__global__ __launch_bounds__(256) void partition_kernel(const int* __restrict__ src,
                                                        const int* __restrict__ dst, int e,
                                                        int epb, int K,
                                                        const int* __restrict__ hist,
                                                        uint_t* __restrict__ ebuf) {
    __shared__ int loff[1024];
    int t = threadIdx.x, b = blockIdx.x;
    for (int k = t; k < K; k += 256) loff[k] = hist[k * PB + b];
    __syncthreads();
    int lo = b * epb, hi = min(lo + epb, e);
    for (int i = lo + t; i < hi; i += 256) {
        int d = dst[i];
        int k = d >> 6;
        int pos = atomicAdd(&loff[k], 1);   // LDS atomic only
        ebuf[pos] = (uint_t)src[i] | ((uint_t)(d & (NPB - 1)) << 16);
    }
}

// per-bucket node counts (replaces 800k-global-atomic count_edges)
__global__ __launch_bounds__(256) void bucket_count_kernel(const uint_t* __restrict__ ebuf,
                                                           const int* __restrict__ hist,
                                                           int e, int K, int n,
                                                           int* __restrict__ cnt) {
    __shared__ int c64[NPB];
    int t = threadIdx.x, k = blockIdx.x;
    if (t < NPB) c64[t] = 0;
    __syncthreads();
    int lo = hist[k * PB];
    int hi = (k + 1 < K) ? hist[(k + 1) * PB] : e;
    for (int i = lo + t; i < hi; i += 256) atomicAdd(&c64[(ebuf[i] >> 16) & (NPB - 1)], 1);
    __syncthreads();
    int node = k * NPB + t;
    if (t < NPB && node < n) cnt[node] = c64[t];
}

// per-bucket CSR fill: writes land in the bucket's ~4KB csr window
__global__ __launch_bounds__(256) void bucket_fill_kernel(const uint_t* __restrict__ ebuf,
                                                          const int* __restrict__ hist,
                                                          const int* __restrict__ rowstart,
                                                          int e, int K, int n,
                                                          int* __restrict__ csr_src) {
    __shared__ int rs[NPB];
    __shared__ int c64[NPB];
    int t = threadIdx.x, k = blockIdx.x;
    if (t < NPB) {
        int node = k * NPB + t;
        rs[t] = (node < n) ? rowstart[node] : 0;
        c64[t] = 0;
    }
    __syncthreads();
    int lo = hist[k * PB];
    int hi = (k + 1 < K) ? hist[(k + 1) * PB] : e;
    for (int i = lo + t; i < hi; i += 256) {
        uint_t u = ebuf[i];
        int dl = (u >> 16) & (NPB - 1);
        int slot = rs[dl] + atomicAdd(&c64[dl], 1);   // LDS atomic only
        csr_src[slot] = (int)(u & 0xffffu);
    }
}

// ---------- GEMM: C_bf16[n,COLS] = dinv[row] * (A[n,128] @ W[128,COLS]) ----------
#define K_DIM 128
template <int COLS>
__global__ __launch_bounds__(256) void gemm_scale_kernel(const float* __restrict__ A,
                                                         const float* __restrict__ W,
                                                         const float* __restrict__ dinv,
                                                         ushort_t* __restrict__ out, int n) {
    constexpr int CG  = COLS / 4;
    constexpr int RG  = 256 / CG;
    constexpr int RPT = 64 / RG;
    __shared__ float Asl[64][132];
    int t    = threadIdx.x;
    int row0 = blockIdx.x * 64;

    #pragma unroll
    for (int it = 0; it < 8; ++it) {
        int idx = (it * 256 + t) * 4;
        int r = idx >> 7;
        int k = idx & 127;
        int gr = row0 + r;
        float4 v = {0.f, 0.f, 0.f, 0.f};
        if (gr < n) v = *(const float4*)&A[gr * K_DIM + k];
        *(float4*)&Asl[r][k] = v;
    }
    __syncthreads();

    int cg = t % CG, rg = t / CG;
    int c0 = cg * 4;
    float acc[RPT][4];
    #pragma unroll
    for (int i = 0; i < RPT; ++i)
        for (int j = 0; j < 4; ++j) acc[i][j] = 0.f;

    for (int k = 0; k < K_DIM; ++k) {
        float4 w = *(const float4*)&W[k * COLS + c0];
        #pragma unroll
        for (int i = 0; i < RPT; ++i) {
            float a = Asl[rg * RPT + i][k];
            acc[i][0] = fmaf(a, w.x, acc[i][0]);
            acc[i][1] = fmaf(a, w.y, acc[i][1]);
            acc[i][2] = fmaf(a, w.z, acc[i][2]);
            acc[i][3] = fmaf(a, w.w, acc[i][3]);
        }
    }

    #pragma unroll
    for (int i = 0; i < RPT; ++i) {
        int r = row0 + rg * RPT + i;
        if (r < n) {
            float s = dinv[r];
            ushort4 o;
            o.x = f2bf(acc[i][0] * s);
            o.y = f2bf(acc[i][1] * s);
            o.z = f2bf(acc[i][2] * s);
            o.w = f2bf(acc[i][3] * s);
            *(ushort4*)&out[r * COLS + c0] = o;
        }
    }
}

// ---------- aggregation: wave = 4 edge-lanes x 16 feat-lanes, 16B/lane ----------

__global__ __launch_bounds__(256) void aggregate128_kernel(const ushort_t* __restrict__ g,
                                                           const int* __restrict__ rowstart,
                                                           const int* __restrict__ csr_src,
                                                           const float* __restrict__ dinv,
                                                           const float* __restrict__ bias,
                                                           float* __restrict__ out, int n) {
    int wave = threadIdx.x >> 6;
    int lane = threadIdx.x & 63;
    int v = blockIdx.x * 4 + wave;
    if (v >= n) return;
    int s    = __builtin_amdgcn_readfirstlane(rowstart[v]);
    int epos = __builtin_amdgcn_readfirstlane(rowstart[v + 1]);
    int eg = lane >> 4;        // edge sub-lane 0..3
    int f  = lane & 15;        // feature group: covers feats f*8..f*8+7

    float a0 = 0.f, a1 = 0.f, a2 = 0.f, a3 = 0.f, a4 = 0.f, a5 = 0.f, a6 = 0.f, a7 = 0.f;
    if (lane < 16) {   // self row
        uint4 m = *(const uint4*)&g[(size_t)v * 128 + f * 8];
        a0 = bf2f_lo(m.x); a1 = bf2f_hi(m.x);
        a2 = bf2f_lo(m.y); a3 = bf2f_hi(m.y);
        a4 = bf2f_lo(m.z); a5 = bf2f_hi(m.z);
        a6 = bf2f_lo(m.w); a7 = bf2f_hi(m.w);
    }

    #pragma unroll 2
    for (int j = s; j < epos; j += 4) {
        int idx = j + eg;
        int safe = min(idx, epos - 1);
        int u = csr_src[safe];
        float w = (idx < epos) ? 1.f : 0.f;
        uint4 m = *(const uint4*)&g[(size_t)u * 128 + f * 8];
        a0 = fmaf(w, bf2f_lo(m.x), a0); a1 = fmaf(w, bf2f_hi(m.x), a1);
        a2 = fmaf(w, bf2f_lo(m.y), a2); a3 = fmaf(w, bf2f_hi(m.y), a3);
        a4 = fmaf(w, bf2f_lo(m.z), a4); a5 = fmaf(w, bf2f_hi(m.z), a5);
        a6 = fmaf(w, bf2f_lo(m.w), a6); a7 = fmaf(w, bf2f_hi(m.w), a7);
    }

    // combine the 4 edge sub-lanes (xor butterfly over lane bits 4,5)
    a0 += __shfl_xor(a0, 16); a1 += __shfl_xor(a1, 16);
    a2 += __shfl_xor(a2, 16); a3 += __shfl_xor(a3, 16);
    a4 += __shfl_xor(a4, 16); a5 += __shfl_xor(a5, 16);
    a6 += __shfl_xor(a6, 16); a7 += __shfl_xor(a7, 16);
    a0 += __shfl_xor(a0, 32); a1 += __shfl_xor(a1, 32);
    a2 += __shfl_xor(a2, 32); a3 += __shfl_xor(a3, 32);
    a4 += __shfl_xor(a4, 32); a5 += __shfl_xor(a5, 32);
    a6 += __shfl_xor(a6, 32); a7 += __shfl_xor(a7, 32);

    if (lane < 16) {
        float dv = dinv[v];
        float4 b0 = *(const float4*)&bias[f * 8];
        float4 b1 = *(const float4*)&bias[f * 8 + 4];
        float4 o0 = {fmaxf(fmaf(a0, dv, b0.x), 0.f), fmaxf(fmaf(a1, dv, b0.y), 0.f),
                     fmaxf(fmaf(a2, dv, b0.z), 0.f), fmaxf(fmaf(a3, dv, b0.w), 0.f)};
        float4 o1 = {fmaxf(fmaf(a4, dv, b1.x), 0.f), fmaxf(fmaf(a5, dv, b1.y), 0.f),
                     fmaxf(fmaf(a6, dv, b1.z), 0.f), fmaxf(fmaf(a7, dv, b1.w), 0.f)};
        *(float4*)&out[(size_t)v * 128 + f * 8] = o0;
        *(float4*)&out[(size_t)v * 128 + f * 8 + 4] = o1;
    }
}

// 64-col variant: wave = 8 edge-lanes x 8 feat-lanes
__global__ __launch_bounds__(256) void aggregate64_kernel(const ushort_t* __restrict__ g,
                                                          const int* __restrict__ rowstart,
                                                          const int* __restrict__ csr_src,
                                                          const float* __restrict__ dinv,
                                                          const float* __restrict__ bias,
                                                          float* __restrict__ out, int n) {
    int wave = threadIdx.x >> 6;
    int lane = threadIdx.x & 63;
    int v = blockIdx.x * 4 + wave;
    if (v >= n) return;
    int s    = __builtin_amdgcn_readfirstlane(rowstart[v]);
    int epos = __builtin_amdgcn_readfirstlane(rowstart[v + 1]);
    int eg = lane >> 3;        // edge sub-lane 0..7
    int f  = lane & 7;         // feats f*8..f*8+7

    float a0 = 0.f, a1 = 0.f, a2 = 0.f, a3 = 0.f, a4 = 0.f, a5 = 0.f, a6 = 0.f, a7 = 0.f;
    if (lane < 8) {   // self row
        uint4 m = *(const uint4*)&g[(size_t)v * 64 + f * 8];
        a0 = bf2f_lo(m.x); a1 = bf2f_hi(m.x);
        a2 = bf2f_lo(m.y); a3 = bf2f_hi(m.y);
        a4 = bf2f_lo(m.z); a5 = bf2f_hi(m.z);
        a6 = bf2f_lo(m.w); a7 = bf2f_hi(m.w);
    }

    #pragma unroll 2
    for (int j = s; j < epos; j += 8) {
        int idx = j + eg;
        int safe = min(idx, epos - 1);
        int u = csr_src[safe];
        float w = (idx < epos) ? 1.f : 0.f;
        uint4 m = *(const uint4*)&g[(size_t)u * 64 + f * 8];
        a0 = fmaf(w, bf2f_lo(m.x), a0); a1 = fmaf(w, bf2f_hi(m.x), a1);
        a2 = fmaf(w, bf2f_lo(m.y), a2); a3 = fmaf(w, bf2f_hi(m.y), a3);
        a4 = fmaf(w, bf2f_lo(m.z), a4); a5 = fmaf(w, bf2f_hi(m.z), a5);
        a6 = fmaf(w, bf2f_lo(m.w), a6); a7 = fmaf(w, bf2f_hi(m.w), a7);
    }

    // combine 8 edge sub-lanes (xor over lane bits 3,4,5)
    a0 += __shfl_xor(a0, 8);  a1 += __shfl_xor(a1, 8);
    a2 += __shfl_xor(a2, 8);  a3 += __shfl_xor(a3, 8);
    a4 += __shfl_xor(a4, 8);  a5 += __shfl_xor(a5, 8);
    a6 += __shfl_xor(a6, 8);  a7 += __shfl_xor(a7, 8);
    a0 += __shfl_xor(a0, 16); a1 += __shfl_xor(a1, 16);
    a2 += __shfl_xor(a2, 16); a3 += __shfl_xor(a3, 16);
    a4 += __shfl_xor(a4, 16); a5 += __shfl_xor(a5, 16);
    a6 += __shfl_xor(a6, 16); a7 += __shfl_xor(a7, 16);
    a0 += __shfl_xor(a0, 32); a1 += __shfl_xor(a1, 32);
    a2 += __shfl_xor(a2, 32); a3 += __shfl_xor(a3, 32);
    a4 += __shfl_xor(a4, 32); a5 += __shfl_xor(a5, 32);
    a6 += __shfl_xor(a6, 32); a7 += __shfl_xor(a7, 32);

    if (lane < 8) {
        float dv = dinv[v];
        float4 b0 = *(const float4*)&bias[f * 8];
        float4 b1 = *(const float4*)&bias[f * 8 + 4];
        float4 o0 = {fmaxf(fmaf(a0, dv, b0.x), 0.f), fmaxf(fmaf(a1, dv, b0.y), 0.f),
                     fmaxf(fmaf(a2, dv, b0.z), 0.f), fmaxf(fmaf(a3, dv, b0.w), 0.f)};
        float4 o1 = {fmaxf(fmaf(a4, dv, b1.x), 0.f), fmaxf(fmaf(a5, dv, b1.y), 0.f),
                     fmaxf(fmaf(a6, dv, b1.z), 0.f), fmaxf(fmaf(a7, dv, b1.w), 0.f)};
        *(float4*)&out[(size_t)v * 64 + f * 8] = o0;
        *(float4*)&out[(size_t)v * 64 + f * 8 + 4] = o1;
    }
}

extern "C" void kernel_launch(void* const* d_in, const int* in_sizes, int n_in,
                              void* d_out, int out_size, void* d_ws, size_t ws_size,
                              hipStream_t stream) {
    const float* x  = (const float*)d_in[0];
    const int*   ei = (const int*)d_in[1];   // [2, E] int32
    const float* W1 = (const float*)d_in[2];
    const float* b1 = (const float*)d_in[3];
    const float* W2 = (const float*)d_in[4];
    const float* b2 = (const float*)d_in[5];
    float* out = (float*)d_out;

    const int n = in_sizes[0] / 128;   // 50000 (must be <= 65536 for packing)
    const int e = in_sizes[1] / 2;     // 800000
    const int* src = ei;
    const int* dst = ei + e;
    const int K   = (n + NPB - 1) / NPB;       // 782 buckets
    const int epb = (e + PB - 1) / PB;         // edges per chunk-block
    const int L   = K * PB;                    // flat histogram length

    char* ws = (char*)d_ws;
    size_t off = 0;
    auto carve = [&](size_t bytes) -> void* {
        void* p = ws + off;
        off = (off + bytes + 255) & ~(size_t)255;
        return p;
    };
    int*      hist     = (int*)     carve((size_t)L * 4);
    int*      bsum     = (int*)     carve((size_t)1024 * 4);
    int*      htotal   = (int*)     carve((size_t)4);
    int*      cnt      = (int*)     carve((size_t)n * 4);
    int*      rowstart = (int*)     carve((size_t)(n + 1) * 4);
    float*    dinv     = (float*)   carve((size_t)n * 4);
    uint_t*   ebuf     = (uint_t*)  carve((size_t)e * 4);
    int*      csr_src  = (int*)     carve((size_t)e * 4);
    ushort_t* g1       = (ushort_t*)carve((size_t)n * 128 * 2);
    float*    h2       = (float*)   carve((size_t)n * 128 * 4);
    ushort_t* g2       = (ushort_t*)carve((size_t)n * 64 * 2);
    (void)ws_size;

    const int nbL = (L + 1023) / 1024;   // hist scan blocks
    const int nbN = (n + 1023) / 1024;   // node scan blocks

    // --- CSR build, zero global atomics, zero memsets ---
    bucket_hist_kernel<<<PB, 256, 0, stream>>>(dst, e, epb, K, hist);
    block_sum_kernel<<<nbL, 256, 0, stream>>>(hist, L, bsum);
    scan_bsum_kernel<<<1, 1024, 0, stream>>>(bsum, nbL, htotal);
    local_scan_apply_kernel<<<nbL, 256, 0, stream>>>(hist, L, bsum);
    partition_kernel<<<PB, 256, 0, stream>>>(src, dst, e, epb, K, hist, ebuf);
    bucket_count_kernel<<<K, 256, 0, stream>>>(ebuf, hist, e, K, n, cnt);
    block_sum_kernel<<<nbN, 256, 0, stream>>>(cnt, n, bsum);
    scan_bsum_kernel<<<1, 1024, 0, stream>>>(bsum, nbN, &rowstart[n]);
    local_scan_kernel<<<nbN, 256, 0, stream>>>(cnt, n, bsum, rowstart, dinv);
    bucket_fill_kernel<<<K, 256, 0, stream>>>(ebuf, hist, rowstart, e, K, n, csr_src);

    // --- layers ---
    const int gblocks = (n + 63) / 64;
    const int ablocks = (n + 3) / 4;
    gemm_scale_kernel<128><<<gblocks, 256, 0, stream>>>(x, W1, dinv, g1, n);
    aggregate128_kernel<<<ablocks, 256, 0, stream>>>(g1, rowstart, csr_src, dinv, b1, h2, n);
    gemm_scale_kernel<64><<<gblocks, 256, 0, stream>>>(h2, W2, dinv, g2, n);
    aggregate64_kernel<<<ablocks, 256, 0, stream>>>(g2, rowstart, csr_src, dinv, b2, out, n);
}